// Round 1
// baseline (1348.835 us; speedup 1.0000x reference)
//
#include <hip/hip_runtime.h>
#include <hip/hip_bf16.h>
#include <hip/hip_fp16.h>

// Problem constants
#define B_    256
#define TR    512
#define P_    128
#define H_    128
#define NG    384      // 3*H
#define KI    256      // 2*P
#define TA    64
#define PSTD  32
#define PSTAT 16
#define HH    64       // HEAD_H
#define FDIM  176      // H + P_STD + P_STATIC

typedef __attribute__((ext_vector_type(8))) short short8;
typedef __attribute__((ext_vector_type(4))) float f32x4;

// ---- helpers ----
__device__ __forceinline__ float bf2f(ushort u) {
    union { uint i; float f; } v; v.i = ((uint)u) << 16; return v.f;
}
__device__ __forceinline__ ushort f2bf(float f) {
    union { float f; uint u; } v; v.f = f;
    uint u = v.u;
    uint r = (u + 0x7fffu + ((u >> 16) & 1u)) >> 16;  // RTNE
    return (ushort)r;
}
__device__ __forceinline__ float sigf(float x) {
    return 1.f / (1.f + __expf(-x));
}

// ---------------------------------------------------------------------------
// Kernel 0: convert Wih, Wd to bf16
// ---------------------------------------------------------------------------
__global__ __launch_bounds__(256) void k_convert(
    const float* __restrict__ Wih, const float* __restrict__ Wd,
    ushort* __restrict__ wih_b, ushort* __restrict__ wd_b)
{
    int i = blockIdx.x * 256 + threadIdx.x;
    if (i < NG * KI) wih_b[i] = f2bf(Wih[i]);
    if (i < H_ * P_) wd_b[i]  = f2bf(Wd[i]);
}

// ---------------------------------------------------------------------------
// Kernel 1: fused elementwise + GEMM (MFMA bf16 16x16x32)
//   A row (per (b,t)): [x_dec(128) | m(128) | x_hat(128)]  (bf16, LDS)
//   outputs: gi[r][0..383] (bf16), h_til[r][0..127] (bf16), delta[r][0..127] (f32)
// ---------------------------------------------------------------------------
#define SA 392   // padded LDS row stride in bf16 elems (392*2=784 B; 784%16==0; 2-way bank aliasing only)

__global__ __launch_bounds__(256) void k_gemm(
    const float* __restrict__ X, const float* __restrict__ M,
    const float* __restrict__ DT, const float* __restrict__ xmean,
    const ushort* __restrict__ wih_b, const ushort* __restrict__ wd_b,
    const float* __restrict__ bih, const float* __restrict__ bd,
    ushort* __restrict__ gi_ws, ushort* __restrict__ htil_ws,
    float* __restrict__ delta_ws)
{
    __shared__ ushort sA[64 * SA];
    const int tid = threadIdx.x;
    const long r0 = (long)blockIdx.x * 64;

    // ---- build A tile (64 rows x 384 cols) + write delta ----
    #pragma unroll 4
    for (int i = 0; i < 32; ++i) {
        int idx = i * 256 + tid;        // 0..8191 = 64 rows x 128 feats
        int rl = idx >> 7, k = idx & 127;
        long g = (r0 + rl) * 128 + k;
        float x = X[g], m = M[g], dt = DT[g], xm = xmean[k];
        float delta = 1.f / (1.f + __expf(dt));   // sigmoid(-dt)
        float xh = m * x + (1.f - m) * xm;
        float xd = m * x + (1.f - m) * (delta * xh + (1.f - delta) * xm);
        sA[rl * SA + k]       = f2bf(xd);
        sA[rl * SA + 128 + k] = f2bf(m);
        sA[rl * SA + 256 + k] = f2bf(xh);
        delta_ws[g] = delta;
    }
    __syncthreads();

    const int wv   = tid >> 6;        // wave 0..3 -> rows 16w..16w+15
    const int lane = tid & 63;
    const int l16  = lane & 15;       // m index for A frag, n index for B frag, col for D
    const int q    = lane >> 4;       // quad
    const int rowbase = wv * 16;

    // ---- gi: 3 parts of 128 cols, K=256 ----
    for (int part = 0; part < 3; ++part) {
        f32x4 acc[8];
        #pragma unroll
        for (int i = 0; i < 8; ++i) acc[i] = (f32x4){0.f, 0.f, 0.f, 0.f};
        #pragma unroll
        for (int ks = 0; ks < 8; ++ks) {
            const short8 a = *(const short8*)&sA[(rowbase + l16) * SA + ks * 32 + q * 8];
            #pragma unroll
            for (int nt = 0; nt < 8; ++nt) {
                int n = part * 128 + nt * 16 + l16;
                const short8 b = *(const short8*)&wih_b[n * KI + ks * 32 + q * 8];
                acc[nt] = __builtin_amdgcn_mfma_f32_16x16x32_bf16(a, b, acc[nt], 0, 0, 0);
            }
        }
        #pragma unroll
        for (int nt = 0; nt < 8; ++nt) {
            int n = part * 128 + nt * 16 + l16;
            float bi = bih[n];
            #pragma unroll
            for (int reg = 0; reg < 4; ++reg) {
                int rl = rowbase + q * 4 + reg;
                gi_ws[(r0 + rl) * NG + n] = f2bf(acc[nt][reg] + bi);
            }
        }
    }

    // ---- h_til: 128 cols, K=128 (A cols 256..383), tanh applied ----
    {
        f32x4 acc[8];
        #pragma unroll
        for (int i = 0; i < 8; ++i) acc[i] = (f32x4){0.f, 0.f, 0.f, 0.f};
        #pragma unroll
        for (int ks = 0; ks < 4; ++ks) {
            const short8 a = *(const short8*)&sA[(rowbase + l16) * SA + 256 + ks * 32 + q * 8];
            #pragma unroll
            for (int nt = 0; nt < 8; ++nt) {
                int n = nt * 16 + l16;
                const short8 b = *(const short8*)&wd_b[n * P_ + ks * 32 + q * 8];
                acc[nt] = __builtin_amdgcn_mfma_f32_16x16x32_bf16(a, b, acc[nt], 0, 0, 0);
            }
        }
        #pragma unroll
        for (int nt = 0; nt < 8; ++nt) {
            int n = nt * 16 + l16;
            float bi = bd[n];
            #pragma unroll
            for (int reg = 0; reg < 4; ++reg) {
                int rl = rowbase + q * 4 + reg;
                htil_ws[(r0 + rl) * P_ + n] = f2bf(tanhf(acc[nt][reg] + bi));
            }
        }
    }
}

// ---------------------------------------------------------------------------
// Kernel 2: recurrent scan. 256 blocks (one per batch row) x 384 threads.
//   thread j owns gh output j; Whh row j lives in 128 f32 VGPRs.
//   threads 0..127 own hidden unit j: h state in register, gates, H_raw store.
// ---------------------------------------------------------------------------
__global__ __launch_bounds__(384, 1) void k_scan(
    const ushort* __restrict__ gi_ws, const ushort* __restrict__ htil_ws,
    const float* __restrict__ delta_ws, const float* __restrict__ Whh,
    const float* __restrict__ bhh, float* __restrict__ Hraw)
{
    __shared__ __align__(16) float s_hpre[2][128];
    __shared__ float s_gh[2][NG];

    const int tid = threadIdx.x;
    const int b = blockIdx.x;
    const long base = (long)b * TR;

    // load my Whh row into registers (128 f32 = 32 float4)
    float4 w4[32];
    const float4* wp = (const float4*)(Whh + tid * H_);
    #pragma unroll
    for (int i = 0; i < 32; ++i) w4[i] = wp[i];
    const float bhh_j = bhh[tid];

    // per-unit state + current-step operands (threads 0..127 only)
    float h = 0.f;
    float d_c = 0.f, ht_c = 0.f, gir_c = 0.f, giz_c = 0.f, gin_c = 0.f;
    if (tid < 128) {
        d_c  = delta_ws[base * P_ + tid];
        ht_c = bf2f(htil_ws[base * P_ + tid]);
        const ushort* gp = gi_ws + base * NG;
        gir_c = bf2f(gp[tid]); giz_c = bf2f(gp[128 + tid]); gin_c = bf2f(gp[256 + tid]);
    }

    int buf = 0;
    float h_pre = 0.f;
    for (int t = 0; t < TR; ++t) {
        float d_n = 0.f, ht_n = 0.f, gir_n = 0.f, giz_n = 0.f, gin_n = 0.f;
        if (tid < 128) {
            h_pre = d_c * h + (1.f - d_c) * ht_c;
            s_hpre[buf][tid] = h_pre;
            // prefetch t+1 operands
            int tn = (t + 1 < TR) ? (t + 1) : t;
            long rn = base + tn;
            d_n  = delta_ws[rn * P_ + tid];
            ht_n = bf2f(htil_ws[rn * P_ + tid]);
            const ushort* gp = gi_ws + rn * NG;
            gir_n = bf2f(gp[tid]); giz_n = bf2f(gp[128 + tid]); gin_n = bf2f(gp[256 + tid]);
        }
        __syncthreads();

        // gh[j] = bhh[j] + Whh[j,:] . h_pre   (all 384 threads)
        {
            const float4* hp4 = (const float4*)s_hpre[buf];
            float a0 = bhh_j, a1 = 0.f, a2 = 0.f, a3 = 0.f;
            #pragma unroll
            for (int c = 0; c < 32; ++c) {
                float4 hp = hp4[c];   // broadcast LDS read (b128)
                float4 ww = w4[c];
                a0 += ww.x * hp.x; a1 += ww.y * hp.y;
                a2 += ww.z * hp.z; a3 += ww.w * hp.w;
            }
            s_gh[buf][tid] = (a0 + a1) + (a2 + a3);
        }
        __syncthreads();

        if (tid < 128) {
            float r = sigf(gir_c + s_gh[buf][tid]);
            float z = sigf(giz_c + s_gh[buf][tid + 128]);
            float n = tanhf(gin_c + r * s_gh[buf][tid + 256]);
            h = (1.f - z) * n + z * h_pre;
            Hraw[(base + t) * H_ + tid] = h;
            d_c = d_n; ht_c = ht_n; gir_c = gir_n; giz_c = giz_n; gin_c = gin_n;
        }
        buf ^= 1;
    }
}

// ---------------------------------------------------------------------------
// Kernel 3: head. 256 blocks (one per batch row) x 256 threads.
//   slot s = tid>>2, part p = tid&3 (16 units each).
// ---------------------------------------------------------------------------
__global__ __launch_bounds__(256) void k_head(
    const float* __restrict__ Hraw, const float* __restrict__ STD,
    const float* __restrict__ Z, const int* __restrict__ idx_map,
    const float* __restrict__ W1, const float* __restrict__ b1,
    const float* __restrict__ W2,
    float* __restrict__ eta, float* __restrict__ Hagg,
    float* __restrict__ mask_out)
{
    __shared__ float sW1[HH * FDIM];
    __shared__ float sb1[HH], sW2[HH];
    __shared__ float spart[TA][4];

    const int tid = threadIdx.x, b = blockIdx.x;
    for (int i = tid; i < HH * FDIM; i += 256) sW1[i] = W1[i];
    if (tid < HH) { sb1[tid] = b1[tid]; sW2[tid] = W2[tid]; }
    __syncthreads();

    const int s = tid >> 2, p = tid & 3;
    const int idx = idx_map[b * TA + s];
    const int valid = idx >= 0;
    const int tt = valid ? idx : 0;
    const float* hrow = Hraw + ((long)b * TR + tt) * H_;

    float acc[16];
    #pragma unroll
    for (int uu = 0; uu < 16; ++uu) acc[uu] = sb1[p * 16 + uu];

    for (int f = 0; f < FDIM; ++f) {
        float feat;
        if (f < H_)              feat = valid ? hrow[f] : 0.f;
        else if (f < H_ + PSTD)  feat = STD[((long)b * TA + s) * PSTD + (f - H_)];
        else                     feat = Z[b * PSTAT + (f - H_ - PSTD)];
        #pragma unroll
        for (int uu = 0; uu < 16; ++uu)
            acc[uu] += feat * sW1[(p * 16 + uu) * FDIM + f];
    }

    float pe = 0.f;
    #pragma unroll
    for (int uu = 0; uu < 16; ++uu) {
        float a = acc[uu];
        pe += (a > 0.f ? a : 0.f) * sW2[p * 16 + uu];
    }
    spart[s][p] = pe;

    // H_agg + mask outputs
    for (int e = 0; e < 32; ++e) {
        int ee = p * 32 + e;
        Hagg[((long)b * TA + s) * H_ + ee] = valid ? hrow[ee] : 0.f;
    }
    if (p == 0) mask_out[b * TA + s] = valid ? 1.f : 0.f;

    __syncthreads();
    if (tid < TA)
        eta[b * TA + tid] = spart[tid][0] + spart[tid][1] + spart[tid][2] + spart[tid][3];
}

// ---------------------------------------------------------------------------
extern "C" void kernel_launch(void* const* d_in, const int* in_sizes, int n_in,
                              void* d_out, int out_size, void* d_ws, size_t ws_size,
                              hipStream_t stream)
{
    const float* X     = (const float*)d_in[0];
    const float* M     = (const float*)d_in[1];
    const float* DT    = (const float*)d_in[2];
    const float* STD   = (const float*)d_in[3];
    const float* Z     = (const float*)d_in[4];
    const int*   idxm  = (const int*)  d_in[5];
    const float* xmean = (const float*)d_in[6];
    const float* Wd    = (const float*)d_in[7];
    const float* bd    = (const float*)d_in[8];
    const float* Wih   = (const float*)d_in[9];
    const float* bih   = (const float*)d_in[10];
    const float* Whh   = (const float*)d_in[11];
    const float* bhh   = (const float*)d_in[12];
    const float* W1    = (const float*)d_in[13];
    const float* b1    = (const float*)d_in[14];
    const float* W2    = (const float*)d_in[15];

    const long RROWS = (long)B_ * TR;   // 131072
    char* ws = (char*)d_ws;
    size_t off = 0;
    ushort* gi_ws   = (ushort*)(ws + off); off += (size_t)RROWS * NG * 2;   // 100663296
    ushort* htil_ws = (ushort*)(ws + off); off += (size_t)RROWS * P_ * 2;   //  33554432
    float*  delta_ws= (float*) (ws + off); off += (size_t)RROWS * P_ * 4;   //  67108864
    ushort* wih_b   = (ushort*)(ws + off); off += (size_t)NG * KI * 2;      //    196608
    ushort* wd_b    = (ushort*)(ws + off); off += (size_t)H_ * P_ * 2;      //     32768

    float* out   = (float*)d_out;
    float* eta   = out;                                  // [256,64]
    float* Hraw  = out + 16384;                          // [256,512,128]
    float* Hagg  = out + 16384 + (long)B_ * TR * H_;     // [256,64,128]
    float* maskO = Hagg + (long)B_ * TA * H_;            // [256,64]

    hipLaunchKernelGGL(k_convert, dim3(384), dim3(256), 0, stream,
                       Wih, Wd, wih_b, wd_b);
    hipLaunchKernelGGL(k_gemm, dim3(2048), dim3(256), 0, stream,
                       X, M, DT, xmean, wih_b, wd_b, bih, bd,
                       gi_ws, htil_ws, delta_ws);
    hipLaunchKernelGGL(k_scan, dim3(256), dim3(384), 0, stream,
                       gi_ws, htil_ws, delta_ws, Whh, bhh, Hraw);
    hipLaunchKernelGGL(k_head, dim3(256), dim3(256), 0, stream,
                       Hraw, STD, Z, idxm, W1, b1, W2, eta, Hagg, maskO);
}

// Round 2
// 1014.979 us; speedup vs baseline: 1.3289x; 1.3289x over previous
//
#include <hip/hip_runtime.h>
#include <hip/hip_bf16.h>
#include <hip/hip_fp16.h>

// Problem constants
#define B_    256
#define TR    512
#define P_    128
#define H_    128
#define NG    384      // 3*H
#define KI    256      // 2*P
#define TA    64
#define PSTD  32
#define PSTAT 16
#define HH    64       // HEAD_H
#define FDIM  176      // H + P_STD + P_STATIC

#define TB    16       // scan time-tile (LDS-resident steps)
#define NT    (TR/TB)  // 32 tiles

typedef __attribute__((ext_vector_type(8))) short short8;
typedef __attribute__((ext_vector_type(4))) float f32x4;

// ---- helpers ----
__device__ __forceinline__ float bf2f(ushort u) {
    union { uint i; float f; } v; v.i = ((uint)u) << 16; return v.f;
}
__device__ __forceinline__ ushort f2bf(float f) {
    union { float f; uint u; } v; v.f = f;
    uint u = v.u;
    uint r = (u + 0x7fffu + ((u >> 16) & 1u)) >> 16;  // RTNE
    return (ushort)r;
}
__device__ __forceinline__ float sigf(float x) {
    return 1.f / (1.f + __expf(-x));
}
__device__ __forceinline__ float tanhf_fast(float x) {
    float ax = fabsf(x);
    float e = __expf(-2.f * ax);          // underflows to 0 for large ax -> r=1
    float r = (1.f - e) / (1.f + e);
    return copysignf(r, x);
}

// ---------------------------------------------------------------------------
// Kernel 0: convert Wih, Wd to bf16
// ---------------------------------------------------------------------------
__global__ __launch_bounds__(256) void k_convert(
    const float* __restrict__ Wih, const float* __restrict__ Wd,
    ushort* __restrict__ wih_b, ushort* __restrict__ wd_b)
{
    int i = blockIdx.x * 256 + threadIdx.x;
    if (i < NG * KI) wih_b[i] = f2bf(Wih[i]);
    if (i < H_ * P_) wd_b[i]  = f2bf(Wd[i]);
}

// ---------------------------------------------------------------------------
// Kernel 1: fused elementwise + GEMM (MFMA bf16 16x16x32)  [unchanged]
// ---------------------------------------------------------------------------
#define SA 392   // padded LDS row stride in bf16 elems

__global__ __launch_bounds__(256) void k_gemm(
    const float* __restrict__ X, const float* __restrict__ M,
    const float* __restrict__ DT, const float* __restrict__ xmean,
    const ushort* __restrict__ wih_b, const ushort* __restrict__ wd_b,
    const float* __restrict__ bih, const float* __restrict__ bd,
    ushort* __restrict__ gi_ws, ushort* __restrict__ htil_ws,
    float* __restrict__ delta_ws)
{
    __shared__ ushort sA[64 * SA];
    const int tid = threadIdx.x;
    const long r0 = (long)blockIdx.x * 64;

    #pragma unroll 4
    for (int i = 0; i < 32; ++i) {
        int idx = i * 256 + tid;
        int rl = idx >> 7, k = idx & 127;
        long g = (r0 + rl) * 128 + k;
        float x = X[g], m = M[g], dt = DT[g], xm = xmean[k];
        float delta = 1.f / (1.f + __expf(dt));   // sigmoid(-dt)
        float xh = m * x + (1.f - m) * xm;
        float xd = m * x + (1.f - m) * (delta * xh + (1.f - delta) * xm);
        sA[rl * SA + k]       = f2bf(xd);
        sA[rl * SA + 128 + k] = f2bf(m);
        sA[rl * SA + 256 + k] = f2bf(xh);
        delta_ws[g] = delta;
    }
    __syncthreads();

    const int wv   = tid >> 6;
    const int lane = tid & 63;
    const int l16  = lane & 15;
    const int q    = lane >> 4;
    const int rowbase = wv * 16;

    for (int part = 0; part < 3; ++part) {
        f32x4 acc[8];
        #pragma unroll
        for (int i = 0; i < 8; ++i) acc[i] = (f32x4){0.f, 0.f, 0.f, 0.f};
        #pragma unroll
        for (int ks = 0; ks < 8; ++ks) {
            const short8 a = *(const short8*)&sA[(rowbase + l16) * SA + ks * 32 + q * 8];
            #pragma unroll
            for (int nt = 0; nt < 8; ++nt) {
                int n = part * 128 + nt * 16 + l16;
                const short8 b = *(const short8*)&wih_b[n * KI + ks * 32 + q * 8];
                acc[nt] = __builtin_amdgcn_mfma_f32_16x16x32_bf16(a, b, acc[nt], 0, 0, 0);
            }
        }
        #pragma unroll
        for (int nt = 0; nt < 8; ++nt) {
            int n = part * 128 + nt * 16 + l16;
            float bi = bih[n];
            #pragma unroll
            for (int reg = 0; reg < 4; ++reg) {
                int rl = rowbase + q * 4 + reg;
                gi_ws[(r0 + rl) * NG + n] = f2bf(acc[nt][reg] + bi);
            }
        }
    }

    {
        f32x4 acc[8];
        #pragma unroll
        for (int i = 0; i < 8; ++i) acc[i] = (f32x4){0.f, 0.f, 0.f, 0.f};
        #pragma unroll
        for (int ks = 0; ks < 4; ++ks) {
            const short8 a = *(const short8*)&sA[(rowbase + l16) * SA + 256 + ks * 32 + q * 8];
            #pragma unroll
            for (int nt = 0; nt < 8; ++nt) {
                int n = nt * 16 + l16;
                const short8 b = *(const short8*)&wd_b[n * P_ + ks * 32 + q * 8];
                acc[nt] = __builtin_amdgcn_mfma_f32_16x16x32_bf16(a, b, acc[nt], 0, 0, 0);
            }
        }
        #pragma unroll
        for (int nt = 0; nt < 8; ++nt) {
            int n = nt * 16 + l16;
            float bi = bd[n];
            #pragma unroll
            for (int reg = 0; reg < 4; ++reg) {
                int rl = rowbase + q * 4 + reg;
                htil_ws[(r0 + rl) * P_ + n] = f2bf(tanhf(acc[nt][reg] + bi));
            }
        }
    }
}

// ---------------------------------------------------------------------------
// Kernel 2: recurrent scan (REWRITTEN).
//   256 blocks (one per batch) x 256 threads (4 waves).
//   Thread pair (j = tid>>1, half = tid&1) owns hidden unit j:
//     - 3 Whh rows (r/z/n), K-half of 64, in 192 f32 VGPRs
//     - partial dots combined via __shfl_xor(.,1) (same wave, no barrier)
//     - half0 applies gates -> ONE barrier per step
//   All global I/O time-tiled through LDS (TB=16 steps) so per-step barriers
//   drain only LDS, never HBM-latency loads/stores.
// ---------------------------------------------------------------------------
__global__ __launch_bounds__(256, 1) void k_scan(
    const ushort* __restrict__ gi_ws, const ushort* __restrict__ htil_ws,
    const float* __restrict__ delta_ws, const float* __restrict__ Whh,
    const float* __restrict__ bhh, float* __restrict__ Hraw)
{
    __shared__ __align__(16) ushort s_gi[TB][NG];      // 12288 B
    __shared__ __align__(16) ushort s_htil[TB][P_];    //  4096 B
    __shared__ __align__(16) float  s_delta[TB][P_];   //  8192 B
    __shared__ __align__(16) float  s_hout[TB][P_];    //  8192 B
    __shared__ __align__(16) float  s_hpre[2][P_];     //  1024 B

    const int tid  = threadIdx.x;
    const int b    = blockIdx.x;
    const int j    = tid >> 1;
    const int half = tid & 1;
    const long base = (long)b * TR;

    // Whh rows for unit j (gates r,z,n), my K-half: 48 float4 = 192 VGPRs
    float4 wv[3][16];
    #pragma unroll
    for (int g = 0; g < 3; ++g) {
        const float4* wp = (const float4*)(Whh + ((g << 7) + j) * H_ + (half << 6));
        #pragma unroll
        for (int i = 0; i < 16; ++i) wv[g][i] = wp[i];
    }
    float bh0 = 0.f, bh1 = 0.f, bh2 = 0.f;
    if (half == 0) { bh0 = bhh[j]; bh1 = bhh[128 + j]; bh2 = bhh[256 + j]; }

    int buf = 0;
    float h = 0.f, h_pre = 0.f;
    float d_c = 0.f, ht_c = 0.f, gr_c = 0.f, gz_c = 0.f, gn_c = 0.f;

    for (int tile = 0; tile < NT; ++tile) {
        const long t0 = (long)tile * TB;
        __syncthreads();   // prev tile: LDS reads done, s_hout writes visible

        if (tile > 0) {    // bulk-store previous tile's Hraw (TB*128 f32 = 512 uint4)
            uint4* dst = (uint4*)(Hraw + (base + (t0 - TB)) * H_);
            const uint4* src = (const uint4*)s_hout;
            #pragma unroll
            for (int i = 0; i < 2; ++i) dst[tid + 256 * i] = src[tid + 256 * i];
        }
        {   // bulk-load this tile's inputs into LDS
            const uint4* g1 = (const uint4*)(gi_ws + (size_t)(base + t0) * NG);
            uint4* d1 = (uint4*)s_gi;                    // 768 uint4
            #pragma unroll
            for (int i = 0; i < 3; ++i) d1[tid + 256 * i] = g1[tid + 256 * i];
            const uint4* g2 = (const uint4*)(htil_ws + (size_t)(base + t0) * P_);
            ((uint4*)s_htil)[tid] = g2[tid];             // 256 uint4
            const uint4* g3 = (const uint4*)(delta_ws + (base + t0) * P_);
            uint4* d3 = (uint4*)s_delta;                 // 512 uint4
            #pragma unroll
            for (int i = 0; i < 2; ++i) d3[tid + 256 * i] = g3[tid + 256 * i];
        }
        __syncthreads();   // inputs visible (the only HBM-draining barrier per tile)

        if (half == 0) {   // preload step-0 operands
            d_c  = s_delta[0][j];
            ht_c = bf2f(s_htil[0][j]);
            gr_c = bf2f(s_gi[0][j]);
            gz_c = bf2f(s_gi[0][128 + j]);
            gn_c = bf2f(s_gi[0][256 + j]);
        }

        for (int ts = 0; ts < TB; ++ts) {
            if (half == 0) {
                h_pre = d_c * h + (1.f - d_c) * ht_c;
                s_hpre[buf][j] = h_pre;
            }
            __syncthreads();   // ONE barrier per step; drains LDS only

            // prefetch next-step operands (LDS, latency hidden by dots)
            float d_n = d_c, ht_n = ht_c, gr_n = gr_c, gz_n = gz_c, gn_n = gn_c;
            if (half == 0 && ts + 1 < TB) {
                d_n  = s_delta[ts + 1][j];
                ht_n = bf2f(s_htil[ts + 1][j]);
                gr_n = bf2f(s_gi[ts + 1][j]);
                gz_n = bf2f(s_gi[ts + 1][128 + j]);
                gn_n = bf2f(s_gi[ts + 1][256 + j]);
            }

            // partial dots over my 64-wide K-half (broadcast LDS reads)
            const float4* hp = (const float4*)&s_hpre[buf][half << 6];
            float ar0 = 0.f, ar1 = 0.f, az0 = 0.f, az1 = 0.f, an0 = 0.f, an1 = 0.f;
            #pragma unroll
            for (int i = 0; i < 16; ++i) {
                float4 hv = hp[i];
                float4 w0 = wv[0][i], w1 = wv[1][i], w2 = wv[2][i];
                float pr = w0.x * hv.x + w0.y * hv.y + w0.z * hv.z + w0.w * hv.w;
                float pz = w1.x * hv.x + w1.y * hv.y + w1.z * hv.z + w1.w * hv.w;
                float pn = w2.x * hv.x + w2.y * hv.y + w2.z * hv.z + w2.w * hv.w;
                if (i & 1) { ar1 += pr; az1 += pz; an1 += pn; }
                else       { ar0 += pr; az0 += pz; an0 += pn; }
            }
            float sr = ar0 + ar1, sz = az0 + az1, sn = an0 + an1;
            sr += __shfl_xor(sr, 1);   // combine K-halves (adjacent lanes, same wave)
            sz += __shfl_xor(sz, 1);
            sn += __shfl_xor(sn, 1);

            if (half == 0) {
                float r = sigf(gr_c + bh0 + sr);
                float z = sigf(gz_c + bh1 + sz);
                float n = tanhf_fast(gn_c + r * (bh2 + sn));
                h = (1.f - z) * n + z * h_pre;
                s_hout[ts][j] = h;
                d_c = d_n; ht_c = ht_n; gr_c = gr_n; gz_c = gz_n; gn_c = gn_n;
            }
            buf ^= 1;
        }
    }

    __syncthreads();   // last tile's s_hout
    {
        uint4* dst = (uint4*)(Hraw + (base + (TR - TB)) * H_);
        const uint4* src = (const uint4*)s_hout;
        #pragma unroll
        for (int i = 0; i < 2; ++i) dst[tid + 256 * i] = src[tid + 256 * i];
    }
}

// ---------------------------------------------------------------------------
// Kernel 3: head. [unchanged]
// ---------------------------------------------------------------------------
__global__ __launch_bounds__(256) void k_head(
    const float* __restrict__ Hraw, const float* __restrict__ STD,
    const float* __restrict__ Z, const int* __restrict__ idx_map,
    const float* __restrict__ W1, const float* __restrict__ b1,
    const float* __restrict__ W2,
    float* __restrict__ eta, float* __restrict__ Hagg,
    float* __restrict__ mask_out)
{
    __shared__ float sW1[HH * FDIM];
    __shared__ float sb1[HH], sW2[HH];
    __shared__ float spart[TA][4];

    const int tid = threadIdx.x, b = blockIdx.x;
    for (int i = tid; i < HH * FDIM; i += 256) sW1[i] = W1[i];
    if (tid < HH) { sb1[tid] = b1[tid]; sW2[tid] = W2[tid]; }
    __syncthreads();

    const int s = tid >> 2, p = tid & 3;
    const int idx = idx_map[b * TA + s];
    const int valid = idx >= 0;
    const int tt = valid ? idx : 0;
    const float* hrow = Hraw + ((long)b * TR + tt) * H_;

    float acc[16];
    #pragma unroll
    for (int uu = 0; uu < 16; ++uu) acc[uu] = sb1[p * 16 + uu];

    for (int f = 0; f < FDIM; ++f) {
        float feat;
        if (f < H_)              feat = valid ? hrow[f] : 0.f;
        else if (f < H_ + PSTD)  feat = STD[((long)b * TA + s) * PSTD + (f - H_)];
        else                     feat = Z[b * PSTAT + (f - H_ - PSTD)];
        #pragma unroll
        for (int uu = 0; uu < 16; ++uu)
            acc[uu] += feat * sW1[(p * 16 + uu) * FDIM + f];
    }

    float pe = 0.f;
    #pragma unroll
    for (int uu = 0; uu < 16; ++uu) {
        float a = acc[uu];
        pe += (a > 0.f ? a : 0.f) * sW2[p * 16 + uu];
    }
    spart[s][p] = pe;

    for (int e = 0; e < 32; ++e) {
        int ee = p * 32 + e;
        Hagg[((long)b * TA + s) * H_ + ee] = valid ? hrow[ee] : 0.f;
    }
    if (p == 0) mask_out[b * TA + s] = valid ? 1.f : 0.f;

    __syncthreads();
    if (tid < TA)
        eta[b * TA + tid] = spart[tid][0] + spart[tid][1] + spart[tid][2] + spart[tid][3];
}

// ---------------------------------------------------------------------------
extern "C" void kernel_launch(void* const* d_in, const int* in_sizes, int n_in,
                              void* d_out, int out_size, void* d_ws, size_t ws_size,
                              hipStream_t stream)
{
    const float* X     = (const float*)d_in[0];
    const float* M     = (const float*)d_in[1];
    const float* DT    = (const float*)d_in[2];
    const float* STD   = (const float*)d_in[3];
    const float* Z     = (const float*)d_in[4];
    const int*   idxm  = (const int*)  d_in[5];
    const float* xmean = (const float*)d_in[6];
    const float* Wd    = (const float*)d_in[7];
    const float* bd    = (const float*)d_in[8];
    const float* Wih   = (const float*)d_in[9];
    const float* bih   = (const float*)d_in[10];
    const float* Whh   = (const float*)d_in[11];
    const float* bhh   = (const float*)d_in[12];
    const float* W1    = (const float*)d_in[13];
    const float* b1    = (const float*)d_in[14];
    const float* W2    = (const float*)d_in[15];

    const long RROWS = (long)B_ * TR;   // 131072
    char* ws = (char*)d_ws;
    size_t off = 0;
    ushort* gi_ws   = (ushort*)(ws + off); off += (size_t)RROWS * NG * 2;
    ushort* htil_ws = (ushort*)(ws + off); off += (size_t)RROWS * P_ * 2;
    float*  delta_ws= (float*) (ws + off); off += (size_t)RROWS * P_ * 4;
    ushort* wih_b   = (ushort*)(ws + off); off += (size_t)NG * KI * 2;
    ushort* wd_b    = (ushort*)(ws + off); off += (size_t)H_ * P_ * 2;

    float* out   = (float*)d_out;
    float* eta   = out;                                  // [256,64]
    float* Hraw  = out + 16384;                          // [256,512,128]
    float* Hagg  = out + 16384 + (long)B_ * TR * H_;     // [256,64,128]
    float* maskO = Hagg + (long)B_ * TA * H_;            // [256,64]

    hipLaunchKernelGGL(k_convert, dim3(384), dim3(256), 0, stream,
                       Wih, Wd, wih_b, wd_b);
    hipLaunchKernelGGL(k_gemm, dim3(2048), dim3(256), 0, stream,
                       X, M, DT, xmean, wih_b, wd_b, bih, bd,
                       gi_ws, htil_ws, delta_ws);
    hipLaunchKernelGGL(k_scan, dim3(256), dim3(256), 0, stream,
                       gi_ws, htil_ws, delta_ws, Whh, bhh, Hraw);
    hipLaunchKernelGGL(k_head, dim3(256), dim3(256), 0, stream,
                       Hraw, STD, Z, idxm, W1, b1, W2, eta, Hagg, maskO);
}

// Round 3
// 920.447 us; speedup vs baseline: 1.4654x; 1.1027x over previous
//
#include <hip/hip_runtime.h>
#include <hip/hip_bf16.h>
#include <hip/hip_fp16.h>

// Problem constants
#define B_    256
#define TR    512
#define P_    128
#define H_    128
#define NG    384      // 3*H
#define KI    256      // 2*P
#define TA    64
#define PSTD  32
#define PSTAT 16
#define HH    64       // HEAD_H
#define FDIM  176      // H + P_STD + P_STATIC

#define TB    16       // scan time-tile (LDS-resident steps)
#define NT    (TR/TB)  // 32 tiles
#define TILE_BYTES 24576   // gi(12288) + htil(4096) + delta(8192) per tile
#define TILE_U4    1536    // TILE_BYTES/16

typedef __attribute__((ext_vector_type(8))) short short8;
typedef __attribute__((ext_vector_type(4))) float f32x4;

// ---- helpers ----
__device__ __forceinline__ float bf2f(ushort u) {
    union { uint i; float f; } v; v.i = ((uint)u) << 16; return v.f;
}
__device__ __forceinline__ ushort f2bf(float f) {
    union { float f; uint u; } v; v.f = f;
    uint u = v.u;
    uint r = (u + 0x7fffu + ((u >> 16) & 1u)) >> 16;  // RTNE
    return (ushort)r;
}
__device__ __forceinline__ float sigf(float x) {
    return 1.f / (1.f + __expf(-x));
}
__device__ __forceinline__ float tanhf_fast(float x) {
    float ax = fabsf(x);
    float e = __expf(-2.f * ax);          // underflows to 0 for large ax -> r=1
    float r = (1.f - e) / (1.f + e);
    return copysignf(r, x);
}
// LDS-only barrier: does NOT drain vmcnt, so global prefetch loads / stores
// stay in flight across per-step syncs. Memory clobber pins ordering.
__device__ __forceinline__ void bar_lds() {
    __asm__ volatile("s_waitcnt lgkmcnt(0)\n\ts_barrier" ::: "memory");
}
// DPP quad-perm adds (lanes 4k..4k+3 form a quad; q = tid&3 lives in-quad)
__device__ __forceinline__ float dpp_add_xor1(float x) {
    int r = __builtin_amdgcn_mov_dpp(__float_as_int(x), 0xB1, 0xF, 0xF, true);
    return x + __int_as_float(r);
}
__device__ __forceinline__ float dpp_add_xor2(float x) {
    int r = __builtin_amdgcn_mov_dpp(__float_as_int(x), 0x4E, 0xF, 0xF, true);
    return x + __int_as_float(r);
}

// ---------------------------------------------------------------------------
// Kernel 0: convert Wih, Wd to bf16
// ---------------------------------------------------------------------------
__global__ __launch_bounds__(256) void k_convert(
    const float* __restrict__ Wih, const float* __restrict__ Wd,
    ushort* __restrict__ wih_b, ushort* __restrict__ wd_b)
{
    int i = blockIdx.x * 256 + threadIdx.x;
    if (i < NG * KI) wih_b[i] = f2bf(Wih[i]);
    if (i < H_ * P_) wd_b[i]  = f2bf(Wd[i]);
}

// ---------------------------------------------------------------------------
// Kernel 1: fused elementwise + GEMM (MFMA bf16 16x16x32)
// ---------------------------------------------------------------------------
#define SA 392   // padded LDS row stride in bf16 elems

__global__ __launch_bounds__(256) void k_gemm(
    const float* __restrict__ X, const float* __restrict__ M,
    const float* __restrict__ DT, const float* __restrict__ xmean,
    const ushort* __restrict__ wih_b, const ushort* __restrict__ wd_b,
    const float* __restrict__ bih, const float* __restrict__ bd,
    ushort* __restrict__ gi_ws, ushort* __restrict__ htil_ws,
    float* __restrict__ delta_ws)
{
    __shared__ ushort sA[64 * SA];
    const int tid = threadIdx.x;
    const long r0 = (long)blockIdx.x * 64;

    #pragma unroll 4
    for (int i = 0; i < 32; ++i) {
        int idx = i * 256 + tid;
        int rl = idx >> 7, k = idx & 127;
        long g = (r0 + rl) * 128 + k;
        float x = X[g], m = M[g], dt = DT[g], xm = xmean[k];
        float delta = 1.f / (1.f + __expf(dt));   // sigmoid(-dt)
        float xh = m * x + (1.f - m) * xm;
        float xd = m * x + (1.f - m) * (delta * xh + (1.f - delta) * xm);
        sA[rl * SA + k]       = f2bf(xd);
        sA[rl * SA + 128 + k] = f2bf(m);
        sA[rl * SA + 256 + k] = f2bf(xh);
        delta_ws[g] = delta;
    }
    __syncthreads();

    const int wv   = tid >> 6;
    const int lane = tid & 63;
    const int l16  = lane & 15;
    const int q    = lane >> 4;
    const int rowbase = wv * 16;

    for (int part = 0; part < 3; ++part) {
        f32x4 acc[8];
        #pragma unroll
        for (int i = 0; i < 8; ++i) acc[i] = (f32x4){0.f, 0.f, 0.f, 0.f};
        #pragma unroll
        for (int ks = 0; ks < 8; ++ks) {
            const short8 a = *(const short8*)&sA[(rowbase + l16) * SA + ks * 32 + q * 8];
            #pragma unroll
            for (int nt = 0; nt < 8; ++nt) {
                int n = part * 128 + nt * 16 + l16;
                const short8 b = *(const short8*)&wih_b[n * KI + ks * 32 + q * 8];
                acc[nt] = __builtin_amdgcn_mfma_f32_16x16x32_bf16(a, b, acc[nt], 0, 0, 0);
            }
        }
        #pragma unroll
        for (int nt = 0; nt < 8; ++nt) {
            int n = part * 128 + nt * 16 + l16;
            float bi = bih[n];
            #pragma unroll
            for (int reg = 0; reg < 4; ++reg) {
                int rl = rowbase + q * 4 + reg;
                gi_ws[(r0 + rl) * NG + n] = f2bf(acc[nt][reg] + bi);
            }
        }
    }

    {
        f32x4 acc[8];
        #pragma unroll
        for (int i = 0; i < 8; ++i) acc[i] = (f32x4){0.f, 0.f, 0.f, 0.f};
        #pragma unroll
        for (int ks = 0; ks < 4; ++ks) {
            const short8 a = *(const short8*)&sA[(rowbase + l16) * SA + 256 + ks * 32 + q * 8];
            #pragma unroll
            for (int nt = 0; nt < 8; ++nt) {
                int n = nt * 16 + l16;
                const short8 b = *(const short8*)&wd_b[n * P_ + ks * 32 + q * 8];
                acc[nt] = __builtin_amdgcn_mfma_f32_16x16x32_bf16(a, b, acc[nt], 0, 0, 0);
            }
        }
        #pragma unroll
        for (int nt = 0; nt < 8; ++nt) {
            int n = nt * 16 + l16;
            float bi = bd[n];
            #pragma unroll
            for (int reg = 0; reg < 4; ++reg) {
                int rl = rowbase + q * 4 + reg;
                htil_ws[(r0 + rl) * P_ + n] = f2bf(tanhf_fast(acc[nt][reg] + bi));
            }
        }
    }
}

// ---------------------------------------------------------------------------
// Kernel 2: recurrent scan v3.
//   256 blocks x 512 threads (8 waves, 2/SIMD). Thread (j=tid>>2, q=tid&3):
//     - 3 Whh rows (r/z/n), K-quarter of 32, in 96 f32 VGPRs
//     - quad-reduce via DPP (in-quad, no LDS, no barrier)
//     - q==0 lane applies gates -> ONE LDS-only barrier per step
//   Input tiles double-buffered in LDS; next tile prefetched into REGISTERS
//   at tile start and kept in flight (raw barriers don't drain vmcnt).
//   s_hpre padded: section q at float offset 36q -> conflict-free reads.
// ---------------------------------------------------------------------------
__global__ __launch_bounds__(512, 2) void k_scan(
    const ushort* __restrict__ gi_ws, const ushort* __restrict__ htil_ws,
    const float* __restrict__ delta_ws, const float* __restrict__ Whh,
    const float* __restrict__ bhh, float* __restrict__ Hraw)
{
    __shared__ __align__(16) char  s_in[2][TILE_BYTES];  // 49152 B
    __shared__ __align__(16) float s_hout[TB * P_];      //  8192 B
    __shared__ __align__(16) float s_hpre[2][144];       //  1152 B

    const int tid = threadIdx.x;
    const int b   = blockIdx.x;
    const int j   = tid >> 2;
    const int q   = tid & 3;
    const long base = (long)b * TR;
    const int hpos = 36 * (j >> 5) + (j & 31);   // padded s_hpre position

    // Whh rows for unit j (gates r,z,n), my K-quarter: 24 float4 = 96 VGPRs
    float4 wv[3][8];
    #pragma unroll
    for (int g = 0; g < 3; ++g) {
        const float4* wp = (const float4*)(Whh + ((g << 7) + j) * H_ + (q << 5));
        #pragma unroll
        for (int i = 0; i < 8; ++i) wv[g][i] = wp[i];
    }
    float bh0 = 0.f, bh1 = 0.f, bh2 = 0.f;
    if (q == 0) { bh0 = bhh[j]; bh1 = bhh[128 + j]; bh2 = bhh[256 + j]; }

    // ---- load tile 0 into s_in[0] ----
    {
        const uint4* gi4 = (const uint4*)(gi_ws   + (size_t)base * NG);
        const uint4* ht4 = (const uint4*)(htil_ws + (size_t)base * P_);
        const uint4* dl4 = (const uint4*)(delta_ws + (size_t)base * P_);
        uint4 p0 = gi4[tid];
        uint4 p1 = (tid < 256) ? gi4[512 + tid] : ht4[tid - 256];
        uint4 p2 = dl4[tid];
        uint4* d = (uint4*)s_in[0];
        d[tid] = p0; d[512 + tid] = p1; d[1024 + tid] = p2;
    }
    bar_lds();

    int cur = 0, sb = 0;
    float h = 0.f, h_pre = 0.f;
    float d_c = 0.f, ht_c = 0.f, gr_c = 0.f, gz_c = 0.f, gn_c = 0.f;

    for (int tile = 0; tile < NT; ++tile) {
        // ---- issue next-tile prefetch into registers (stays in flight) ----
        uint4 p0, p1, p2;
        const int has_next = (tile + 1 < NT);
        if (has_next) {
            const long tn = base + (long)(tile + 1) * TB;
            const uint4* gi4 = (const uint4*)(gi_ws   + (size_t)tn * NG);
            const uint4* ht4 = (const uint4*)(htil_ws + (size_t)tn * P_);
            const uint4* dl4 = (const uint4*)(delta_ws + (size_t)tn * P_);
            p0 = gi4[tid];
            p1 = (tid < 256) ? gi4[512 + tid] : ht4[tid - 256];
            p2 = dl4[tid];
        }

        const ushort* sgi = (const ushort*)s_in[cur];                  // [TB][NG]
        const ushort* sht = (const ushort*)(s_in[cur] + 12288);        // [TB][P_]
        const float*  sdl = (const float*) (s_in[cur] + 16384);        // [TB][P_]

        if (q == 0) {   // step-0 operands
            d_c  = sdl[j];
            ht_c = bf2f(sht[j]);
            gr_c = bf2f(sgi[j]);
            gz_c = bf2f(sgi[128 + j]);
            gn_c = bf2f(sgi[256 + j]);
        }

        for (int ts = 0; ts < TB; ++ts) {
            if (q == 0) {
                h_pre = d_c * h + (1.f - d_c) * ht_c;
                s_hpre[sb][hpos] = h_pre;
            }
            bar_lds();   // LDS-only: prefetch loads stay in flight

            // next-step operands (LDS reads hidden under the dots)
            float d_n = d_c, ht_n = ht_c, gr_n = gr_c, gz_n = gz_c, gn_n = gn_c;
            if (q == 0 && ts + 1 < TB) {
                d_n  = sdl[(ts + 1) * P_ + j];
                ht_n = bf2f(sht[(ts + 1) * P_ + j]);
                gr_n = bf2f(sgi[(ts + 1) * NG + j]);
                gz_n = bf2f(sgi[(ts + 1) * NG + 128 + j]);
                gn_n = bf2f(sgi[(ts + 1) * NG + 256 + j]);
            }

            // partial dots over my 32-wide K-quarter (conflict-free b128 reads)
            const float4* hp = (const float4*)&s_hpre[sb][q * 36];
            float ar0 = 0.f, ar1 = 0.f, az0 = 0.f, az1 = 0.f, an0 = 0.f, an1 = 0.f;
            #pragma unroll
            for (int i = 0; i < 8; ++i) {
                float4 hv = hp[i];
                float4 w0 = wv[0][i], w1 = wv[1][i], w2 = wv[2][i];
                float pr = w0.x * hv.x + w0.y * hv.y + w0.z * hv.z + w0.w * hv.w;
                float pz = w1.x * hv.x + w1.y * hv.y + w1.z * hv.z + w1.w * hv.w;
                float pn = w2.x * hv.x + w2.y * hv.y + w2.z * hv.z + w2.w * hv.w;
                if (i & 1) { ar1 += pr; az1 += pz; an1 += pn; }
                else       { ar0 += pr; az0 += pz; an0 += pn; }
            }
            float sr = ar0 + ar1, sz = az0 + az1, sn = an0 + an1;
            sr = dpp_add_xor2(dpp_add_xor1(sr));   // quad reduce, VALU-only
            sz = dpp_add_xor2(dpp_add_xor1(sz));
            sn = dpp_add_xor2(dpp_add_xor1(sn));

            if (q == 0) {
                float r = sigf(gr_c + bh0 + sr);
                float z = sigf(gz_c + bh1 + sz);
                float n = tanhf_fast(gn_c + r * (bh2 + sn));
                h = (1.f - z) * n + z * h_pre;
                s_hout[ts * P_ + j] = h;
                d_c = d_n; ht_c = ht_n; gr_c = gr_n; gz_c = gz_n; gn_c = gn_n;
            }
            sb ^= 1;
        }

        bar_lds();   // s_hout complete; last step's s_hpre reads done

        // bulk-store this tile's Hraw (fire-and-forget; raw barriers don't drain)
        {
            uint4* dst = (uint4*)(Hraw + (base + (long)tile * TB) * H_);
            dst[tid] = ((const uint4*)s_hout)[tid];
        }
        // commit register prefetch into the other LDS tile buffer
        if (has_next) {
            uint4* d = (uint4*)s_in[cur ^ 1];
            d[tid] = p0; d[512 + tid] = p1; d[1024 + tid] = p2;
        }
        bar_lds();   // tile inputs visible; s_hout ds_reads retired
        cur ^= 1;
    }
}

// ---------------------------------------------------------------------------
// Kernel 3: head. [unchanged]
// ---------------------------------------------------------------------------
__global__ __launch_bounds__(256) void k_head(
    const float* __restrict__ Hraw, const float* __restrict__ STD,
    const float* __restrict__ Z, const int* __restrict__ idx_map,
    const float* __restrict__ W1, const float* __restrict__ b1,
    const float* __restrict__ W2,
    float* __restrict__ eta, float* __restrict__ Hagg,
    float* __restrict__ mask_out)
{
    __shared__ float sW1[HH * FDIM];
    __shared__ float sb1[HH], sW2[HH];
    __shared__ float spart[TA][4];

    const int tid = threadIdx.x, b = blockIdx.x;
    for (int i = tid; i < HH * FDIM; i += 256) sW1[i] = W1[i];
    if (tid < HH) { sb1[tid] = b1[tid]; sW2[tid] = W2[tid]; }
    __syncthreads();

    const int s = tid >> 2, p = tid & 3;
    const int idx = idx_map[b * TA + s];
    const int valid = idx >= 0;
    const int tt = valid ? idx : 0;
    const float* hrow = Hraw + ((long)b * TR + tt) * H_;

    float acc[16];
    #pragma unroll
    for (int uu = 0; uu < 16; ++uu) acc[uu] = sb1[p * 16 + uu];

    for (int f = 0; f < FDIM; ++f) {
        float feat;
        if (f < H_)              feat = valid ? hrow[f] : 0.f;
        else if (f < H_ + PSTD)  feat = STD[((long)b * TA + s) * PSTD + (f - H_)];
        else                     feat = Z[b * PSTAT + (f - H_ - PSTD)];
        #pragma unroll
        for (int uu = 0; uu < 16; ++uu)
            acc[uu] += feat * sW1[(p * 16 + uu) * FDIM + f];
    }

    float pe = 0.f;
    #pragma unroll
    for (int uu = 0; uu < 16; ++uu) {
        float a = acc[uu];
        pe += (a > 0.f ? a : 0.f) * sW2[p * 16 + uu];
    }
    spart[s][p] = pe;

    for (int e = 0; e < 32; ++e) {
        int ee = p * 32 + e;
        Hagg[((long)b * TA + s) * H_ + ee] = valid ? hrow[ee] : 0.f;
    }
    if (p == 0) mask_out[b * TA + s] = valid ? 1.f : 0.f;

    __syncthreads();
    if (tid < TA)
        eta[b * TA + tid] = spart[tid][0] + spart[tid][1] + spart[tid][2] + spart[tid][3];
}

// ---------------------------------------------------------------------------
extern "C" void kernel_launch(void* const* d_in, const int* in_sizes, int n_in,
                              void* d_out, int out_size, void* d_ws, size_t ws_size,
                              hipStream_t stream)
{
    const float* X     = (const float*)d_in[0];
    const float* M     = (const float*)d_in[1];
    const float* DT    = (const float*)d_in[2];
    const float* STD   = (const float*)d_in[3];
    const float* Z     = (const float*)d_in[4];
    const int*   idxm  = (const int*)  d_in[5];
    const float* xmean = (const float*)d_in[6];
    const float* Wd    = (const float*)d_in[7];
    const float* bd    = (const float*)d_in[8];
    const float* Wih   = (const float*)d_in[9];
    const float* bih   = (const float*)d_in[10];
    const float* Whh   = (const float*)d_in[11];
    const float* bhh   = (const float*)d_in[12];
    const float* W1    = (const float*)d_in[13];
    const float* b1    = (const float*)d_in[14];
    const float* W2    = (const float*)d_in[15];

    const long RROWS = (long)B_ * TR;   // 131072
    char* ws = (char*)d_ws;
    size_t off = 0;
    ushort* gi_ws   = (ushort*)(ws + off); off += (size_t)RROWS * NG * 2;
    ushort* htil_ws = (ushort*)(ws + off); off += (size_t)RROWS * P_ * 2;
    float*  delta_ws= (float*) (ws + off); off += (size_t)RROWS * P_ * 4;
    ushort* wih_b   = (ushort*)(ws + off); off += (size_t)NG * KI * 2;
    ushort* wd_b    = (ushort*)(ws + off); off += (size_t)H_ * P_ * 2;

    float* out   = (float*)d_out;
    float* eta   = out;                                  // [256,64]
    float* Hraw  = out + 16384;                          // [256,512,128]
    float* Hagg  = out + 16384 + (long)B_ * TR * H_;     // [256,64,128]
    float* maskO = Hagg + (long)B_ * TA * H_;            // [256,64]

    hipLaunchKernelGGL(k_convert, dim3(384), dim3(256), 0, stream,
                       Wih, Wd, wih_b, wd_b);
    hipLaunchKernelGGL(k_gemm, dim3(2048), dim3(256), 0, stream,
                       X, M, DT, xmean, wih_b, wd_b, bih, bd,
                       gi_ws, htil_ws, delta_ws);
    hipLaunchKernelGGL(k_scan, dim3(256), dim3(512), 0, stream,
                       gi_ws, htil_ws, delta_ws, Whh, bhh, Hraw);
    hipLaunchKernelGGL(k_head, dim3(256), dim3(256), 0, stream,
                       Hraw, STD, Z, idxm, W1, b1, W2, eta, Hagg, maskO);
}

// Round 4
// 770.169 us; speedup vs baseline: 1.7513x; 1.1951x over previous
//
#include <hip/hip_runtime.h>
#include <hip/hip_bf16.h>
#include <hip/hip_fp16.h>

// Problem constants
#define B_    256
#define TR    512
#define P_    128
#define H_    128
#define NG    384      // 3*H
#define KI    256      // 2*P
#define TA    64
#define PSTD  32
#define PSTAT 16
#define HH    64       // HEAD_H
#define FDIM  176      // H + P_STD + P_STATIC

#define TB    16       // scan time-tile (LDS-resident steps)
#define NT    (TR/TB)  // 32 tiles
#define TILE_BYTES 24576   // gi(12288) + htil(4096) + delta(8192) per tile

typedef __attribute__((ext_vector_type(8))) short short8;
typedef __attribute__((ext_vector_type(4))) float f32x4;

// ---- helpers ----
__device__ __forceinline__ float bf2f(ushort u) {
    union { uint i; float f; } v; v.i = ((uint)u) << 16; return v.f;
}
__device__ __forceinline__ ushort f2bf(float f) {
    union { float f; uint u; } v; v.f = f;
    uint u = v.u;
    uint r = (u + 0x7fffu + ((u >> 16) & 1u)) >> 16;  // RTNE
    return (ushort)r;
}
__device__ __forceinline__ float sigf(float x) {
    return 1.f / (1.f + __expf(-x));
}
__device__ __forceinline__ float tanhf_fast(float x) {
    float ax = fabsf(x);
    float e = __expf(-2.f * ax);          // underflows to 0 for large ax -> r=1
    float r = (1.f - e) / (1.f + e);
    return copysignf(r, x);
}
// LDS-only barrier: does NOT drain vmcnt.
__device__ __forceinline__ void bar_lds() {
    __asm__ volatile("s_waitcnt lgkmcnt(0)\n\ts_barrier" ::: "memory");
}
// DPP quad-perm adds
__device__ __forceinline__ float dpp_add_xor1(float x) {
    int r = __builtin_amdgcn_mov_dpp(__float_as_int(x), 0xB1, 0xF, 0xF, true);
    return x + __int_as_float(r);
}
__device__ __forceinline__ float dpp_add_xor2(float x) {
    int r = __builtin_amdgcn_mov_dpp(__float_as_int(x), 0x4E, 0xF, 0xF, true);
    return x + __int_as_float(r);
}

// ---------------------------------------------------------------------------
// Kernel 0: convert Wih, Wd to bf16
// ---------------------------------------------------------------------------
__global__ __launch_bounds__(256) void k_convert(
    const float* __restrict__ Wih, const float* __restrict__ Wd,
    ushort* __restrict__ wih_b, ushort* __restrict__ wd_b)
{
    int i = blockIdx.x * 256 + threadIdx.x;
    if (i < NG * KI) wih_b[i] = f2bf(Wih[i]);
    if (i < H_ * P_) wd_b[i]  = f2bf(Wd[i]);
}

// ---------------------------------------------------------------------------
// Kernel 1: fused elementwise + GEMM v2 (MFMA bf16 16x16x32).
//   Block: 64 rows. Wave w: ALL 64 rows x 96-col slice (4x6 acc tiles) for gi,
//   64 rows x 32-col slice for htil. 4x less B traffic than v1.
//   Epilogue stages bf16 results in LDS (reusing sA) -> fully coalesced
//   contiguous uint4 global stores (v1 did scattered 2-byte stores: the
//   ~470us bottleneck).
// ---------------------------------------------------------------------------
#define SA 392   // padded LDS row stride in bf16 elems (also >= 384 for staging)

__global__ __launch_bounds__(256, 2) void k_gemm(
    const float* __restrict__ X, const float* __restrict__ M,
    const float* __restrict__ DT, const float* __restrict__ xmean,
    const ushort* __restrict__ wih_b, const ushort* __restrict__ wd_b,
    const float* __restrict__ bih, const float* __restrict__ bd,
    ushort* __restrict__ gi_ws, ushort* __restrict__ htil_ws,
    float* __restrict__ delta_ws)
{
    __shared__ __align__(16) ushort sA[64 * SA];   // 50176 B; reused for staging
    const int tid = threadIdx.x;
    const long r0 = (long)blockIdx.x * 64;

    // ---- build A tile (64 rows x [x_dec|m|x_hat]) + delta (coalesced f32) ----
    #pragma unroll 4
    for (int i = 0; i < 32; ++i) {
        int idx = i * 256 + tid;
        int rl = idx >> 7, k = idx & 127;
        long g = (r0 + rl) * 128 + k;
        float x = X[g], m = M[g], dt = DT[g], xm = xmean[k];
        float delta = 1.f / (1.f + __expf(dt));   // sigmoid(-dt)
        float xh = m * x + (1.f - m) * xm;
        float xd = m * x + (1.f - m) * (delta * xh + (1.f - delta) * xm);
        sA[rl * SA + k]       = f2bf(xd);
        sA[rl * SA + 128 + k] = f2bf(m);
        sA[rl * SA + 256 + k] = f2bf(xh);
        delta_ws[g] = delta;
    }
    __syncthreads();

    const int wv   = tid >> 6;        // wave 0..3 -> gi col slice [96w,96w+96)
    const int lane = tid & 63;
    const int l16  = lane & 15;       // A row idx / B col idx / C col idx
    const int q    = lane >> 4;       // quad: A k-offset q*8 / C rows q*4+reg

    // ---- gi: acc[rt][nt], rt = row-tile (16 rows), nt = col-tile in slice ----
    f32x4 acc[4][6];
    #pragma unroll
    for (int rt = 0; rt < 4; ++rt)
        #pragma unroll
        for (int nt = 0; nt < 6; ++nt) acc[rt][nt] = (f32x4){0.f, 0.f, 0.f, 0.f};

    const int nb = 96 * wv;
    #pragma unroll
    for (int ks = 0; ks < 8; ++ks) {
        short8 a[4];
        #pragma unroll
        for (int rt = 0; rt < 4; ++rt)
            a[rt] = *(const short8*)&sA[(rt * 16 + l16) * SA + ks * 32 + q * 8];
        #pragma unroll
        for (int nt = 0; nt < 6; ++nt) {
            const short8 b = *(const short8*)&wih_b[(size_t)(nb + nt * 16 + l16) * KI + ks * 32 + q * 8];
            #pragma unroll
            for (int rt = 0; rt < 4; ++rt)
                acc[rt][nt] = __builtin_amdgcn_mfma_f32_16x16x32_bf16(a[rt], b, acc[rt][nt], 0, 0, 0);
        }
    }

    // ---- htil: acc2[rt][nt2], col slice [32w,32w+32), K=128 (A cols 256+) ----
    f32x4 acc2[4][2];
    #pragma unroll
    for (int rt = 0; rt < 4; ++rt)
        #pragma unroll
        for (int nt = 0; nt < 2; ++nt) acc2[rt][nt] = (f32x4){0.f, 0.f, 0.f, 0.f};

    const int nb2 = 32 * wv;
    #pragma unroll
    for (int ks = 0; ks < 4; ++ks) {
        short8 a[4];
        #pragma unroll
        for (int rt = 0; rt < 4; ++rt)
            a[rt] = *(const short8*)&sA[(rt * 16 + l16) * SA + 256 + ks * 32 + q * 8];
        #pragma unroll
        for (int nt = 0; nt < 2; ++nt) {
            const short8 b = *(const short8*)&wd_b[(size_t)(nb2 + nt * 16 + l16) * P_ + ks * 32 + q * 8];
            #pragma unroll
            for (int rt = 0; rt < 4; ++rt)
                acc2[rt][nt] = __builtin_amdgcn_mfma_f32_16x16x32_bf16(a[rt], b, acc2[rt][nt], 0, 0, 0);
        }
    }

    __syncthreads();   // all sA reads done; safe to overwrite with staging

    // ---- stage gi (bf16, [row][n] unpadded 64x384) into sA region ----
    ushort* sOut = sA;
    #pragma unroll
    for (int nt = 0; nt < 6; ++nt) {
        const int n = nb + nt * 16 + l16;
        const float bi = bih[n];
        #pragma unroll
        for (int rt = 0; rt < 4; ++rt) {
            #pragma unroll
            for (int reg = 0; reg < 4; ++reg) {
                int row = rt * 16 + q * 4 + reg;
                sOut[row * NG + n] = f2bf(acc[rt][nt][reg] + bi);
            }
        }
    }
    __syncthreads();

    // ---- coalesced contiguous store: 64*384 bf16 = 3072 uint4 ----
    {
        uint4* dst = (uint4*)(gi_ws + (size_t)r0 * NG);
        const uint4* src = (const uint4*)sOut;
        #pragma unroll
        for (int i = 0; i < 12; ++i) dst[tid + 256 * i] = src[tid + 256 * i];
    }
    __syncthreads();   // uint4 LDS reads retired; safe to restage

    // ---- stage htil (bf16, [row][n] 64x128) ----
    #pragma unroll
    for (int nt = 0; nt < 2; ++nt) {
        const int n = nb2 + nt * 16 + l16;
        const float bi = bd[n];
        #pragma unroll
        for (int rt = 0; rt < 4; ++rt) {
            #pragma unroll
            for (int reg = 0; reg < 4; ++reg) {
                int row = rt * 16 + q * 4 + reg;
                sOut[row * P_ + n] = f2bf(tanhf_fast(acc2[rt][nt][reg] + bi));
            }
        }
    }
    __syncthreads();

    // ---- coalesced store: 64*128 bf16 = 1024 uint4 ----
    {
        uint4* dst = (uint4*)(htil_ws + (size_t)r0 * P_);
        const uint4* src = (const uint4*)sOut;
        #pragma unroll
        for (int i = 0; i < 4; ++i) dst[tid + 256 * i] = src[tid + 256 * i];
    }
}

// ---------------------------------------------------------------------------
// Kernel 2: recurrent scan v3. [unchanged from R3]
// ---------------------------------------------------------------------------
__global__ __launch_bounds__(512, 2) void k_scan(
    const ushort* __restrict__ gi_ws, const ushort* __restrict__ htil_ws,
    const float* __restrict__ delta_ws, const float* __restrict__ Whh,
    const float* __restrict__ bhh, float* __restrict__ Hraw)
{
    __shared__ __align__(16) char  s_in[2][TILE_BYTES];  // 49152 B
    __shared__ __align__(16) float s_hout[TB * P_];      //  8192 B
    __shared__ __align__(16) float s_hpre[2][144];       //  1152 B

    const int tid = threadIdx.x;
    const int b   = blockIdx.x;
    const int j   = tid >> 2;
    const int q   = tid & 3;
    const long base = (long)b * TR;
    const int hpos = 36 * (j >> 5) + (j & 31);   // padded s_hpre position

    float4 wv[3][8];
    #pragma unroll
    for (int g = 0; g < 3; ++g) {
        const float4* wp = (const float4*)(Whh + ((g << 7) + j) * H_ + (q << 5));
        #pragma unroll
        for (int i = 0; i < 8; ++i) wv[g][i] = wp[i];
    }
    float bh0 = 0.f, bh1 = 0.f, bh2 = 0.f;
    if (q == 0) { bh0 = bhh[j]; bh1 = bhh[128 + j]; bh2 = bhh[256 + j]; }

    {
        const uint4* gi4 = (const uint4*)(gi_ws   + (size_t)base * NG);
        const uint4* ht4 = (const uint4*)(htil_ws + (size_t)base * P_);
        const uint4* dl4 = (const uint4*)(delta_ws + (size_t)base * P_);
        uint4 p0 = gi4[tid];
        uint4 p1 = (tid < 256) ? gi4[512 + tid] : ht4[tid - 256];
        uint4 p2 = dl4[tid];
        uint4* d = (uint4*)s_in[0];
        d[tid] = p0; d[512 + tid] = p1; d[1024 + tid] = p2;
    }
    bar_lds();

    int cur = 0, sb = 0;
    float h = 0.f, h_pre = 0.f;
    float d_c = 0.f, ht_c = 0.f, gr_c = 0.f, gz_c = 0.f, gn_c = 0.f;

    for (int tile = 0; tile < NT; ++tile) {
        uint4 p0, p1, p2;
        const int has_next = (tile + 1 < NT);
        if (has_next) {
            const long tn = base + (long)(tile + 1) * TB;
            const uint4* gi4 = (const uint4*)(gi_ws   + (size_t)tn * NG);
            const uint4* ht4 = (const uint4*)(htil_ws + (size_t)tn * P_);
            const uint4* dl4 = (const uint4*)(delta_ws + (size_t)tn * P_);
            p0 = gi4[tid];
            p1 = (tid < 256) ? gi4[512 + tid] : ht4[tid - 256];
            p2 = dl4[tid];
        }

        const ushort* sgi = (const ushort*)s_in[cur];
        const ushort* sht = (const ushort*)(s_in[cur] + 12288);
        const float*  sdl = (const float*) (s_in[cur] + 16384);

        if (q == 0) {
            d_c  = sdl[j];
            ht_c = bf2f(sht[j]);
            gr_c = bf2f(sgi[j]);
            gz_c = bf2f(sgi[128 + j]);
            gn_c = bf2f(sgi[256 + j]);
        }

        for (int ts = 0; ts < TB; ++ts) {
            if (q == 0) {
                h_pre = d_c * h + (1.f - d_c) * ht_c;
                s_hpre[sb][hpos] = h_pre;
            }
            bar_lds();

            float d_n = d_c, ht_n = ht_c, gr_n = gr_c, gz_n = gz_c, gn_n = gn_c;
            if (q == 0 && ts + 1 < TB) {
                d_n  = sdl[(ts + 1) * P_ + j];
                ht_n = bf2f(sht[(ts + 1) * P_ + j]);
                gr_n = bf2f(sgi[(ts + 1) * NG + j]);
                gz_n = bf2f(sgi[(ts + 1) * NG + 128 + j]);
                gn_n = bf2f(sgi[(ts + 1) * NG + 256 + j]);
            }

            const float4* hp = (const float4*)&s_hpre[sb][q * 36];
            float ar0 = 0.f, ar1 = 0.f, az0 = 0.f, az1 = 0.f, an0 = 0.f, an1 = 0.f;
            #pragma unroll
            for (int i = 0; i < 8; ++i) {
                float4 hv = hp[i];
                float4 w0 = wv[0][i], w1 = wv[1][i], w2 = wv[2][i];
                float pr = w0.x * hv.x + w0.y * hv.y + w0.z * hv.z + w0.w * hv.w;
                float pz = w1.x * hv.x + w1.y * hv.y + w1.z * hv.z + w1.w * hv.w;
                float pn = w2.x * hv.x + w2.y * hv.y + w2.z * hv.z + w2.w * hv.w;
                if (i & 1) { ar1 += pr; az1 += pz; an1 += pn; }
                else       { ar0 += pr; az0 += pz; an0 += pn; }
            }
            float sr = ar0 + ar1, sz = az0 + az1, sn = an0 + an1;
            sr = dpp_add_xor2(dpp_add_xor1(sr));
            sz = dpp_add_xor2(dpp_add_xor1(sz));
            sn = dpp_add_xor2(dpp_add_xor1(sn));

            if (q == 0) {
                float r = sigf(gr_c + bh0 + sr);
                float z = sigf(gz_c + bh1 + sz);
                float n = tanhf_fast(gn_c + r * (bh2 + sn));
                h = (1.f - z) * n + z * h_pre;
                s_hout[ts * P_ + j] = h;
                d_c = d_n; ht_c = ht_n; gr_c = gr_n; gz_c = gz_n; gn_c = gn_n;
            }
            sb ^= 1;
        }

        bar_lds();

        {
            uint4* dst = (uint4*)(Hraw + (base + (long)tile * TB) * H_);
            dst[tid] = ((const uint4*)s_hout)[tid];
        }
        if (has_next) {
            uint4* d = (uint4*)s_in[cur ^ 1];
            d[tid] = p0; d[512 + tid] = p1; d[1024 + tid] = p2;
        }
        bar_lds();
        cur ^= 1;
    }
}

// ---------------------------------------------------------------------------
// Kernel 3: head. [unchanged]
// ---------------------------------------------------------------------------
__global__ __launch_bounds__(256) void k_head(
    const float* __restrict__ Hraw, const float* __restrict__ STD,
    const float* __restrict__ Z, const int* __restrict__ idx_map,
    const float* __restrict__ W1, const float* __restrict__ b1,
    const float* __restrict__ W2,
    float* __restrict__ eta, float* __restrict__ Hagg,
    float* __restrict__ mask_out)
{
    __shared__ float sW1[HH * FDIM];
    __shared__ float sb1[HH], sW2[HH];
    __shared__ float spart[TA][4];

    const int tid = threadIdx.x, b = blockIdx.x;
    for (int i = tid; i < HH * FDIM; i += 256) sW1[i] = W1[i];
    if (tid < HH) { sb1[tid] = b1[tid]; sW2[tid] = W2[tid]; }
    __syncthreads();

    const int s = tid >> 2, p = tid & 3;
    const int idx = idx_map[b * TA + s];
    const int valid = idx >= 0;
    const int tt = valid ? idx : 0;
    const float* hrow = Hraw + ((long)b * TR + tt) * H_;

    float acc[16];
    #pragma unroll
    for (int uu = 0; uu < 16; ++uu) acc[uu] = sb1[p * 16 + uu];

    for (int f = 0; f < FDIM; ++f) {
        float feat;
        if (f < H_)              feat = valid ? hrow[f] : 0.f;
        else if (f < H_ + PSTD)  feat = STD[((long)b * TA + s) * PSTD + (f - H_)];
        else                     feat = Z[b * PSTAT + (f - H_ - PSTD)];
        #pragma unroll
        for (int uu = 0; uu < 16; ++uu)
            acc[uu] += feat * sW1[(p * 16 + uu) * FDIM + f];
    }

    float pe = 0.f;
    #pragma unroll
    for (int uu = 0; uu < 16; ++uu) {
        float a = acc[uu];
        pe += (a > 0.f ? a : 0.f) * sW2[p * 16 + uu];
    }
    spart[s][p] = pe;

    for (int e = 0; e < 32; ++e) {
        int ee = p * 32 + e;
        Hagg[((long)b * TA + s) * H_ + ee] = valid ? hrow[ee] : 0.f;
    }
    if (p == 0) mask_out[b * TA + s] = valid ? 1.f : 0.f;

    __syncthreads();
    if (tid < TA)
        eta[b * TA + tid] = spart[tid][0] + spart[tid][1] + spart[tid][2] + spart[tid][3];
}

// ---------------------------------------------------------------------------
extern "C" void kernel_launch(void* const* d_in, const int* in_sizes, int n_in,
                              void* d_out, int out_size, void* d_ws, size_t ws_size,
                              hipStream_t stream)
{
    const float* X     = (const float*)d_in[0];
    const float* M     = (const float*)d_in[1];
    const float* DT    = (const float*)d_in[2];
    const float* STD   = (const float*)d_in[3];
    const float* Z     = (const float*)d_in[4];
    const int*   idxm  = (const int*)  d_in[5];
    const float* xmean = (const float*)d_in[6];
    const float* Wd    = (const float*)d_in[7];
    const float* bd    = (const float*)d_in[8];
    const float* Wih   = (const float*)d_in[9];
    const float* bih   = (const float*)d_in[10];
    const float* Whh   = (const float*)d_in[11];
    const float* bhh   = (const float*)d_in[12];
    const float* W1    = (const float*)d_in[13];
    const float* b1    = (const float*)d_in[14];
    const float* W2    = (const float*)d_in[15];

    const long RROWS = (long)B_ * TR;   // 131072
    char* ws = (char*)d_ws;
    size_t off = 0;
    ushort* gi_ws   = (ushort*)(ws + off); off += (size_t)RROWS * NG * 2;
    ushort* htil_ws = (ushort*)(ws + off); off += (size_t)RROWS * P_ * 2;
    float*  delta_ws= (float*) (ws + off); off += (size_t)RROWS * P_ * 4;
    ushort* wih_b   = (ushort*)(ws + off); off += (size_t)NG * KI * 2;
    ushort* wd_b    = (ushort*)(ws + off); off += (size_t)H_ * P_ * 2;

    float* out   = (float*)d_out;
    float* eta   = out;                                  // [256,64]
    float* Hraw  = out + 16384;                          // [256,512,128]
    float* Hagg  = out + 16384 + (long)B_ * TR * H_;     // [256,64,128]
    float* maskO = Hagg + (long)B_ * TA * H_;            // [256,64]

    hipLaunchKernelGGL(k_convert, dim3(384), dim3(256), 0, stream,
                       Wih, Wd, wih_b, wd_b);
    hipLaunchKernelGGL(k_gemm, dim3(2048), dim3(256), 0, stream,
                       X, M, DT, xmean, wih_b, wd_b, bih, bd,
                       gi_ws, htil_ws, delta_ws);
    hipLaunchKernelGGL(k_scan, dim3(256), dim3(512), 0, stream,
                       gi_ws, htil_ws, delta_ws, Whh, bhh, Hraw);
    hipLaunchKernelGGL(k_head, dim3(256), dim3(256), 0, stream,
                       Hraw, STD, Z, idxm, W1, b1, W2, eta, Hagg, maskO);
}